// Round 6
// baseline (1479.863 us; speedup 1.0000x reference)
//
#include <hip/hip_runtime.h>
#include <math.h>

#define N_NODES 30000
#define D_IN    256
#define E_EDGES 300000
#define T_TYPES 2
#define HEADS   8
#define HID     64
#define F1      512   // HEADS*HID
#define OUT_F   256
#define EP      (E_EDGES + N_NODES)   // 330000 edges per type incl self-loops

typedef __attribute__((ext_vector_type(8))) short bf16x8;
typedef __attribute__((ext_vector_type(4))) float f32x4;

__device__ __forceinline__ unsigned short f2bf(float f) {
    unsigned u = __float_as_uint(f);
    unsigned r = 0x7fffu + ((u >> 16) & 1u);
    return (unsigned short)((u + r) >> 16);
}
__device__ __forceinline__ float bf2f(unsigned short h) {
    return __uint_as_float(((unsigned)h) << 16);
}

// ---------------------------------------------------------------------------
// Fused prep: weight transpose+bf16 hi/lo split (conv1, conv2, lin) + zero the
// per-destination counters. One launch.
// ---------------------------------------------------------------------------
#define PREP_W1   (8 * 65536)
#define PREP_W2   (4 * 131072)
#define PREP_WL   65536
#define PREP_CNT  (T_TYPES * N_NODES)
#define PREP_TOT  (PREP_W1 + PREP_W2 + PREP_WL + PREP_CNT)

__global__ void prep_kernel(const float* __restrict__ w1_l, const float* __restrict__ w1_r,
                            const float* __restrict__ w2_l, const float* __restrict__ w2_r,
                            const float* __restrict__ w_lin,
                            unsigned short* __restrict__ wt1h, unsigned short* __restrict__ wt1l,
                            unsigned short* __restrict__ wt2h, unsigned short* __restrict__ wt2l,
                            unsigned short* __restrict__ wtLh, unsigned short* __restrict__ wtLl,
                            int* __restrict__ count) {
    int idx = blockIdx.x * blockDim.x + threadIdx.x;
    if (idx < PREP_W1) {
        int n = idx & 255, k = (idx >> 8) & 255, mat = idx >> 16;
        int h = mat & 1, lr = (mat >> 1) & 1, t = mat >> 2;
        const float* src = lr ? w1_r : w1_l;
        float v = src[(size_t)t * 256 * 512 + (size_t)k * 512 + h * 256 + n];
        unsigned short hi = f2bf(v);
        unsigned short lo = f2bf(v - bf2f(hi));
        size_t o = (size_t)mat * 65536 + (size_t)n * 256 + k;
        wt1h[o] = hi; wt1l[o] = lo;
        return;
    }
    idx -= PREP_W1;
    if (idx < PREP_W2) {
        int n = idx & 255, k = (idx >> 8) & 511, mat = idx >> 17;
        int lr = mat & 1, t = mat >> 1;
        const float* src = lr ? w2_r : w2_l;
        float v = src[(size_t)t * 512 * 256 + (size_t)k * 256 + n];
        unsigned short hi = f2bf(v);
        unsigned short lo = f2bf(v - bf2f(hi));
        size_t o = (size_t)mat * 131072 + (size_t)n * 512 + k;
        wt2h[o] = hi; wt2l[o] = lo;
        return;
    }
    idx -= PREP_W2;
    if (idx < PREP_WL) {
        int n = idx & 255, k = idx >> 8;
        float v = w_lin[k * 256 + n];
        unsigned short hi = f2bf(v);
        unsigned short lo = f2bf(v - bf2f(hi));
        size_t o = (size_t)n * 256 + k;
        wtLh[o] = hi; wtLl[o] = lo;
        return;
    }
    idx -= PREP_WL;
    if (idx < PREP_CNT) count[idx] = 0;
}

// ---------------------------------------------------------------------------
// CSR build: histogram -> parallel 3-stage scan -> scatter.
// ---------------------------------------------------------------------------
__global__ void hist_kernel(const int* __restrict__ ei, int* __restrict__ count) {
    int idx = blockIdx.x * blockDim.x + threadIdx.x;
    if (idx >= T_TYPES * EP) return;
    int t = idx / EP, i = idx - t * EP;
    int dst = (i < E_EDGES) ? ei[t * 2 * E_EDGES + E_EDGES + i] : (i - E_EDGES);
    atomicAdd(&count[t * N_NODES + dst], 1);
}

#define SCAN_NB 30   // blocks per type, 1024 elems each (30720 >= 30000)

__global__ __launch_bounds__(256) void scan_bsum_kernel(const int* __restrict__ cnt,
                                                        int* __restrict__ bsum) {
    int t = blockIdx.y, b = blockIdx.x;
    const int* c = cnt + t * N_NODES;
    int i0 = b * 1024 + threadIdx.x * 4;
    int s = 0;
    #pragma unroll
    for (int j = 0; j < 4; ++j) { int i = i0 + j; if (i < N_NODES) s += c[i]; }
    #pragma unroll
    for (int m = 1; m < 64; m <<= 1) s += __shfl_xor(s, m);
    __shared__ int wsum[4];
    int l = threadIdx.x & 63, w = threadIdx.x >> 6;
    if (l == 0) wsum[w] = s;
    __syncthreads();
    if (threadIdx.x == 0) bsum[t * SCAN_NB + b] = wsum[0] + wsum[1] + wsum[2] + wsum[3];
}

__global__ void scan_base_kernel(int* __restrict__ bsum) {
    int t = threadIdx.x;
    if (t >= T_TYPES) return;
    int acc = 0;
    for (int b = 0; b < SCAN_NB; ++b) {
        int v = bsum[t * SCAN_NB + b];
        bsum[t * SCAN_NB + b] = acc;
        acc += v;
    }
}

__global__ __launch_bounds__(256) void scan_write_kernel(int* __restrict__ cnt,
                                                         const int* __restrict__ bsum,
                                                         int* __restrict__ off) {
    int t = blockIdx.y, b = blockIdx.x;
    int tid = threadIdx.x;
    int* c = cnt + t * N_NODES;
    int* o = off + t * (N_NODES + 1);
    int i0 = b * 1024 + tid * 4;
    int v[4]; int s = 0;
    #pragma unroll
    for (int j = 0; j < 4; ++j) { int i = i0 + j; v[j] = (i < N_NODES) ? c[i] : 0; s += v[j]; }
    __shared__ int ps[256];
    ps[tid] = s;
    __syncthreads();
    for (int ofs = 1; ofs < 256; ofs <<= 1) {
        int x = (tid >= ofs) ? ps[tid - ofs] : 0;
        __syncthreads();
        ps[tid] += x;
        __syncthreads();
    }
    int base = bsum[t * SCAN_NB + b] + ps[tid] - s;
    #pragma unroll
    for (int j = 0; j < 4; ++j) {
        int i = i0 + j;
        if (i < N_NODES) { o[i] = base; base += v[j]; c[i] = 0; }
    }
    if (b == 0 && tid == 0) o[N_NODES] = EP;
}

__global__ void scatter_kernel(const int* __restrict__ ei, const int* __restrict__ offsets,
                               int* __restrict__ cursor, int* __restrict__ csr_src) {
    int idx = blockIdx.x * blockDim.x + threadIdx.x;
    if (idx >= T_TYPES * EP) return;
    int t = idx / EP, i = idx - t * EP;
    int src, dst;
    if (i < E_EDGES) {
        src = ei[t * 2 * E_EDGES + i];
        dst = ei[t * 2 * E_EDGES + E_EDGES + i];
    } else {
        src = dst = i - E_EDGES;
    }
    int pos = offsets[t * (N_NODES + 1) + dst] + atomicAdd(&cursor[t * N_NODES + dst], 1);
    csr_src[t * EP + pos] = src;
}

// ---------------------------------------------------------------------------
// Split-precision bf16x3 MFMA GEMM, dual-output (blockIdx.y selects B/bias/C).
// ASPLIT=0: A fp32 [M][lda], split in-kernel.  ASPLIT=1: A pre-split bf16
// hi/lo [M][lda].  Tile BM=64 x BN=256 x BK=32, 4 waves, 4x4 16x16x32 frags.
// Register prefetch pipeline: tile k+1 global loads issued before compute of
// tile k (reg loads stay in flight across s_barrier); single LDS buffer.
// Both A and B tiles XOR-granule-swizzled -> conflict-free b128 reads.
// ---------------------------------------------------------------------------
template <int ASPLIT>
__global__ __launch_bounds__(256, 3) void gemm_mfma_kernel(
        const void* __restrict__ A0v, const void* __restrict__ A1v, int lda,
        const unsigned short* __restrict__ Bh0, const unsigned short* __restrict__ Bl0,
        const float* __restrict__ bias0, float* __restrict__ C0,
        const unsigned short* __restrict__ Bh1, const unsigned short* __restrict__ Bl1,
        const float* __restrict__ bias1, float* __restrict__ C1,
        int M, int K) {
    const unsigned short* Bh = blockIdx.y ? Bh1 : Bh0;
    const unsigned short* Bl = blockIdx.y ? Bl1 : Bl0;
    const float* bias = blockIdx.y ? bias1 : bias0;
    float* C = blockIdx.y ? C1 : C0;
    const float* Af          = (const float*)A0v;
    const unsigned short* Ah = (const unsigned short*)A0v;
    const unsigned short* Al = (const unsigned short*)A1v;

    __shared__ unsigned short Ah_s[64 * 32], Al_s[64 * 32];
    __shared__ unsigned short Bh_s[256 * 32], Bl_s[256 * 32];
    int t = threadIdx.x;
    int row0 = blockIdx.x * 64;
    int w = t >> 6;
    int l = t & 63;
    int fm = l & 15;
    int fg = l >> 4;

    f32x4 acc[4][4];
    const f32x4 zf = {0.f, 0.f, 0.f, 0.f};
    #pragma unroll
    for (int i = 0; i < 4; ++i)
        #pragma unroll
        for (int j = 0; j < 4; ++j) acc[i][j] = zf;

    int ar = t >> 3, af = t & 7;     // ASPLIT0: rows ar, ar+32; floats af*4
    int ar1 = t >> 2, ac1 = t & 3;   // ASPLIT1: row ar1, 8-short chunk ac1
    int bn = t >> 2, bb = t & 3;     // B: rows g*64+bn, 8-short chunk bb

    float4 aP[2];
    uint4 ahP, alP;
    uint4 bhP[4], blP[4];

    auto load_tile = [&](int k0) {
        if constexpr (ASPLIT == 0) {
            #pragma unroll
            for (int v = 0; v < 2; ++v) {
                int rg = row0 + v * 32 + ar;
                aP[v] = make_float4(0.f, 0.f, 0.f, 0.f);
                if (rg < M) aP[v] = *(const float4*)&Af[(size_t)rg * lda + k0 + af * 4];
            }
        } else {
            int rg = row0 + ar1;
            ahP = make_uint4(0, 0, 0, 0);
            alP = make_uint4(0, 0, 0, 0);
            if (rg < M) {
                ahP = *(const uint4*)&Ah[(size_t)rg * lda + k0 + ac1 * 8];
                alP = *(const uint4*)&Al[(size_t)rg * lda + k0 + ac1 * 8];
            }
        }
        #pragma unroll
        for (int g = 0; g < 4; ++g) {
            int n = g * 64 + bn;
            bhP[g] = *(const uint4*)&Bh[(size_t)n * K + k0 + bb * 8];
            blP[g] = *(const uint4*)&Bl[(size_t)n * K + k0 + bb * 8];
        }
    };

    load_tile(0);
    for (int k0 = 0; k0 < K; k0 += 32) {
        // ---- stage prefetched regs -> LDS (swizzled) ----
        if constexpr (ASPLIT == 0) {
            #pragma unroll
            for (int v = 0; v < 2; ++v) {
                int r = v * 32 + ar;
                ushort4 hi, lo;
                hi.x = f2bf(aP[v].x); lo.x = f2bf(aP[v].x - bf2f(hi.x));
                hi.y = f2bf(aP[v].y); lo.y = f2bf(aP[v].y - bf2f(hi.y));
                hi.z = f2bf(aP[v].z); lo.z = f2bf(aP[v].z - bf2f(hi.z));
                hi.w = f2bf(aP[v].w); lo.w = f2bf(aP[v].w - bf2f(hi.w));
                int ke = (af * 4) ^ (((r >> 1) & 3) << 3);
                *(ushort4*)&Ah_s[r * 32 + ke] = hi;
                *(ushort4*)&Al_s[r * 32 + ke] = lo;
            }
        } else {
            int ke = (ac1 * 8) ^ (((ar1 >> 1) & 3) << 3);
            *(uint4*)&Ah_s[ar1 * 32 + ke] = ahP;
            *(uint4*)&Al_s[ar1 * 32 + ke] = alP;
        }
        #pragma unroll
        for (int g = 0; g < 4; ++g) {
            int n = g * 64 + bn;
            int ke = (bb * 8) ^ (((n >> 1) & 3) << 3);
            *(uint4*)&Bh_s[n * 32 + ke] = bhP[g];
            *(uint4*)&Bl_s[n * 32 + ke] = blP[g];
        }
        if (k0 + 32 < K) load_tile(k0 + 32);   // next tile in flight across barrier
        __syncthreads();
        // ---- fragments (swizzled reads, conflict-free) ----
        bf16x8 ahf[4], alf[4], bhf[4], blf[4];
        #pragma unroll
        for (int i = 0; i < 4; ++i) {
            int r = i * 16 + fm;
            int ke = (fg * 8) ^ (((r >> 1) & 3) << 3);
            ahf[i] = *(const bf16x8*)&Ah_s[r * 32 + ke];
            alf[i] = *(const bf16x8*)&Al_s[r * 32 + ke];
        }
        #pragma unroll
        for (int j = 0; j < 4; ++j) {
            int n = w * 64 + j * 16 + fm;
            int ke = (fg * 8) ^ (((n >> 1) & 3) << 3);
            bhf[j] = *(const bf16x8*)&Bh_s[n * 32 + ke];
            blf[j] = *(const bf16x8*)&Bl_s[n * 32 + ke];
        }
        #pragma unroll
        for (int i = 0; i < 4; ++i)
            #pragma unroll
            for (int j = 0; j < 4; ++j) {
                acc[i][j] = __builtin_amdgcn_mfma_f32_16x16x32_bf16(ahf[i], bhf[j], acc[i][j], 0, 0, 0);
                acc[i][j] = __builtin_amdgcn_mfma_f32_16x16x32_bf16(ahf[i], blf[j], acc[i][j], 0, 0, 0);
                acc[i][j] = __builtin_amdgcn_mfma_f32_16x16x32_bf16(alf[i], bhf[j], acc[i][j], 0, 0, 0);
            }
        __syncthreads();
    }
    // ---- epilogue (C/D map: col=lane&15, row=(lane>>4)*4+q) ----
    #pragma unroll
    for (int j = 0; j < 4; ++j) {
        int col = w * 64 + j * 16 + fm;
        float bv = bias[col];
        #pragma unroll
        for (int i = 0; i < 4; ++i) {
            #pragma unroll
            for (int q = 0; q < 4; ++q) {
                int rg = row0 + i * 16 + fg * 4 + q;
                if (rg < M) C[(size_t)rg * 256 + col] = acc[i][j][q] + bv;
            }
        }
    }
}

// ---------------------------------------------------------------------------
// Fused GATv2 edge kernel over a 256-column block. One wave per destination.
// MODE 0: out = result (fp32).
// MODE 2: out = elu(out + result + eb0 + eb1)  (fp32).
// MODE 3: v = elu(out + result + eb0 + eb1); write bf16 hi/lo split to sh/sl.
// ---------------------------------------------------------------------------
template <int RW, int MODE>
__global__ __launch_bounds__(256) void gat_edge_kernel(
        const float* __restrict__ xl, const float* __restrict__ xr,
        const float* __restrict__ att,
        const int* __restrict__ offs, const int* __restrict__ csr,
        float* __restrict__ out, int ldo,
        const float* __restrict__ eb0, const float* __restrict__ eb1,
        unsigned short* __restrict__ sh, unsigned short* __restrict__ sl) {
    int wave = (blockIdx.x * blockDim.x + threadIdx.x) >> 6;
    int lane = threadIdx.x & 63;
    if (wave >= N_NODES) return;
    int d = wave;
    int q4 = lane * 4;
    float attr[4], xrr[4];
    *(float4*)&attr[0] = *(const float4*)&att[q4];
    *(float4*)&xrr[0]  = *(const float4*)&xr[(size_t)d * 256 + q4];
    float m = -INFINITY, s = 0.f;
    float acc[4] = {0.f, 0.f, 0.f, 0.f};
    int p0 = offs[d], p1 = offs[d + 1];
    int p = p0;
    for (; p + 2 <= p1; p += 2) {
        int s0 = csr[p], s1 = csr[p + 1];
        float xv0[4], xv1[4];
        *(float4*)&xv0[0] = *(const float4*)&xl[(size_t)s0 * 256 + q4];
        *(float4*)&xv1[0] = *(const float4*)&xl[(size_t)s1 * 256 + q4];
        float e0 = 0.f, e1 = 0.f;
        #pragma unroll
        for (int q = 0; q < 4; ++q) {
            float h0 = xv0[q] + xrr[q];
            float h1 = xv1[q] + xrr[q];
            h0 = (h0 > 0.f) ? h0 : 0.2f * h0;
            h1 = (h1 > 0.f) ? h1 : 0.2f * h1;
            e0 += attr[q] * h0;
            e1 += attr[q] * h1;
        }
        #pragma unroll
        for (int msk = 1; msk < RW; msk <<= 1) {
            e0 += __shfl_xor(e0, msk);
            e1 += __shfl_xor(e1, msk);
        }
        float mn = fmaxf(m, e0);
        float sc = __expf(m - mn);
        float pe = __expf(e0 - mn);
        s = s * sc + pe;
        #pragma unroll
        for (int q = 0; q < 4; ++q) acc[q] = acc[q] * sc + pe * xv0[q];
        m = mn;
        mn = fmaxf(m, e1);
        sc = __expf(m - mn);
        pe = __expf(e1 - mn);
        s = s * sc + pe;
        #pragma unroll
        for (int q = 0; q < 4; ++q) acc[q] = acc[q] * sc + pe * xv1[q];
        m = mn;
    }
    if (p < p1) {
        int s0 = csr[p];
        float xv0[4];
        *(float4*)&xv0[0] = *(const float4*)&xl[(size_t)s0 * 256 + q4];
        float e0 = 0.f;
        #pragma unroll
        for (int q = 0; q < 4; ++q) {
            float h0 = xv0[q] + xrr[q];
            h0 = (h0 > 0.f) ? h0 : 0.2f * h0;
            e0 += attr[q] * h0;
        }
        #pragma unroll
        for (int msk = 1; msk < RW; msk <<= 1) e0 += __shfl_xor(e0, msk);
        float mn = fmaxf(m, e0);
        float sc = __expf(m - mn);
        float pe = __expf(e0 - mn);
        s = s * sc + pe;
        #pragma unroll
        for (int q = 0; q < 4; ++q) acc[q] = acc[q] * sc + pe * xv0[q];
        m = mn;
    }
    float inv = 1.f / s;
    float* dp = &out[(size_t)d * ldo + q4];
    if (MODE == 0) {
        *(float4*)dp = make_float4(acc[0] * inv, acc[1] * inv, acc[2] * inv, acc[3] * inv);
    } else if (MODE == 2) {
        #pragma unroll
        for (int q = 0; q < 4; ++q) {
            float v = dp[q] + acc[q] * inv + eb0[q4 + q] + eb1[q4 + q];
            dp[q] = (v > 0.f) ? v : (__expf(v) - 1.f);
        }
    } else {   // MODE 3: elu + bf16 hi/lo split write
        ushort4 hv, lv;
        float v0 = dp[0] + acc[0] * inv + eb0[q4 + 0] + eb1[q4 + 0];
        float v1 = dp[1] + acc[1] * inv + eb0[q4 + 1] + eb1[q4 + 1];
        float v2 = dp[2] + acc[2] * inv + eb0[q4 + 2] + eb1[q4 + 2];
        float v3 = dp[3] + acc[3] * inv + eb0[q4 + 3] + eb1[q4 + 3];
        v0 = (v0 > 0.f) ? v0 : (__expf(v0) - 1.f);
        v1 = (v1 > 0.f) ? v1 : (__expf(v1) - 1.f);
        v2 = (v2 > 0.f) ? v2 : (__expf(v2) - 1.f);
        v3 = (v3 > 0.f) ? v3 : (__expf(v3) - 1.f);
        hv.x = f2bf(v0); lv.x = f2bf(v0 - bf2f(hv.x));
        hv.y = f2bf(v1); lv.y = f2bf(v1 - bf2f(hv.y));
        hv.z = f2bf(v2); lv.z = f2bf(v2 - bf2f(hv.z));
        hv.w = f2bf(v3); lv.w = f2bf(v3 - bf2f(hv.w));
        *(ushort4*)&sh[(size_t)d * ldo + q4] = hv;
        *(ushort4*)&sl[(size_t)d * ldo + q4] = lv;
    }
}

// ---------------------------------------------------------------------------
extern "C" void kernel_launch(void* const* d_in, const int* in_sizes, int n_in,
                              void* d_out, int out_size, void* d_ws, size_t ws_size,
                              hipStream_t stream) {
    const float* x      = (const float*)d_in[0];
    const int*   ei     = (const int*)d_in[1];
    const float* w1_l   = (const float*)d_in[2];
    const float* b1_l   = (const float*)d_in[3];
    const float* w1_r   = (const float*)d_in[4];
    const float* b1_r   = (const float*)d_in[5];
    const float* att1   = (const float*)d_in[6];
    const float* bias1  = (const float*)d_in[7];
    const float* w2_l   = (const float*)d_in[8];
    const float* b2_l   = (const float*)d_in[9];
    const float* w2_r   = (const float*)d_in[10];
    const float* b2_r   = (const float*)d_in[11];
    const float* att2   = (const float*)d_in[12];
    const float* bias2  = (const float*)d_in[13];
    const float* w_lin  = (const float*)d_in[14];
    const float* b_lin  = (const float*)d_in[15];
    float* out = (float*)d_out;

    // ---- workspace layout (~130 MB, unchanged) ----
    float* h1   = (float*)d_ws;                        // [N][512]  61.44 MB
    float* bufA = h1 + (size_t)N_NODES * F1;           // [N][256]  30.72 MB
    float* bufB = bufA + (size_t)N_NODES * OUT_F;      // [N][256]  30.72 MB
    unsigned short* wt1h = (unsigned short*)(bufB + (size_t)N_NODES * OUT_F);
    unsigned short* wt1l = wt1h + 8 * 65536;
    unsigned short* wt2h = wt1l + 8 * 65536;
    unsigned short* wt2l = wt2h + 4 * 131072;
    unsigned short* wtLh = wt2l + 4 * 131072;
    unsigned short* wtLl = wtLh + 65536;
    int* count   = (int*)(wtLl + 65536);
    int* offsets = count + T_TYPES * N_NODES;
    int* bsum    = offsets + T_TYPES * (N_NODES + 1);
    int* csr     = bsum + T_TYPES * SCAN_NB;
    // h2 split overlays h1's storage (h1 fp32 is dead once conv2 GEMMs read it)
    unsigned short* h2s_hi = (unsigned short*)h1;
    unsigned short* h2s_lo = h2s_hi + (size_t)N_NODES * OUT_F;

    // --- prep (weights split + count zero) ---
    prep_kernel<<<(PREP_TOT + 255) / 256, 256, 0, stream>>>(
        w1_l, w1_r, w2_l, w2_r, w_lin, wt1h, wt1l, wt2h, wt2l, wtLh, wtLl, count);

    // --- build CSR (by dst), shared by both convs ---
    int eblocks = (T_TYPES * EP + 255) / 256;
    hist_kernel<<<eblocks, 256, 0, stream>>>(ei, count);
    dim3 sgrid(SCAN_NB, T_TYPES);
    scan_bsum_kernel<<<sgrid, 256, 0, stream>>>(count, bsum);
    scan_base_kernel<<<1, 64, 0, stream>>>(bsum);
    scan_write_kernel<<<sgrid, 256, 0, stream>>>(count, bsum, offsets);
    scatter_kernel<<<eblocks, 256, 0, stream>>>(ei, offsets, count, csr);

    int gat_blocks = N_NODES / 4;
    dim3 ggrid((N_NODES + 63) / 64, 2);   // dual-output GEMM
    dim3 ggrid1((N_NODES + 63) / 64, 1);  // single-output GEMM

    // --- conv1: per (t, head-half): l+r GEMMs in one launch, then edge kernel ---
    for (int t = 0; t < T_TYPES; ++t) {
        for (int hh = 0; hh < 2; ++hh) {
            int co = hh * 256;
            int ml = (t * 2 + 0) * 2 + hh, mr = (t * 2 + 1) * 2 + hh;
            gemm_mfma_kernel<0><<<ggrid, 256, 0, stream>>>(
                x, nullptr, D_IN,
                wt1h + (size_t)ml * 65536, wt1l + (size_t)ml * 65536, b1_l + t * F1 + co, bufA,
                wt1h + (size_t)mr * 65536, wt1l + (size_t)mr * 65536, b1_r + t * F1 + co, bufB,
                N_NODES, D_IN);
            if (t == 0)
                gat_edge_kernel<16, 0><<<gat_blocks, 256, 0, stream>>>(
                    bufA, bufB, att1 + t * F1 + co, offsets + t * (N_NODES + 1),
                    csr + (size_t)t * EP, h1 + co, F1, nullptr, nullptr, nullptr, nullptr);
            else
                gat_edge_kernel<16, 2><<<gat_blocks, 256, 0, stream>>>(
                    bufA, bufB, att1 + t * F1 + co, offsets + t * (N_NODES + 1),
                    csr + (size_t)t * EP, h1 + co, F1, bias1 + co, bias1 + F1 + co,
                    nullptr, nullptr);
        }
    }

    // --- conv2 (1 head, 256 cols); t1 edge writes pre-split h2 ---
    for (int t = 0; t < T_TYPES; ++t) {
        int ml = t * 2 + 0, mr = t * 2 + 1;
        gemm_mfma_kernel<0><<<ggrid, 256, 0, stream>>>(
            h1, nullptr, F1,
            wt2h + (size_t)ml * 131072, wt2l + (size_t)ml * 131072, b2_l + t * OUT_F, bufA,
            wt2h + (size_t)mr * 131072, wt2l + (size_t)mr * 131072, b2_r + t * OUT_F, bufB,
            N_NODES, F1);
        if (t == 0)
            gat_edge_kernel<64, 0><<<gat_blocks, 256, 0, stream>>>(
                bufA, bufB, att2 + t * OUT_F, offsets + t * (N_NODES + 1),
                csr + (size_t)t * EP, out, OUT_F, nullptr, nullptr, nullptr, nullptr);
        else
            gat_edge_kernel<64, 3><<<gat_blocks, 256, 0, stream>>>(
                bufA, bufB, att2 + t * OUT_F, offsets + t * (N_NODES + 1),
                csr + (size_t)t * EP, out, OUT_F, bias2, bias2 + OUT_F,
                h2s_hi, h2s_lo);
    }

    // --- final linear: reads pre-split h2, writes d_out (no copy, no alias) ---
    gemm_mfma_kernel<1><<<ggrid1, 256, 0, stream>>>(
        h2s_hi, h2s_lo, OUT_F,
        wtLh, wtLl, b_lin, out,
        wtLh, wtLl, b_lin, out,
        N_NODES, OUT_F);
}

// Round 8
// 892.340 us; speedup vs baseline: 1.6584x; 1.6584x over previous
//
#include <hip/hip_runtime.h>
#include <math.h>

#define N_NODES 30000
#define D_IN    256
#define E_EDGES 300000
#define T_TYPES 2
#define HEADS   8
#define HID     64
#define F1      512   // HEADS*HID
#define OUT_F   256
#define EP      (E_EDGES + N_NODES)   // 330000 edges per type incl self-loops

typedef __attribute__((ext_vector_type(8))) short bf16x8;
typedef __attribute__((ext_vector_type(4))) float f32x4;

__device__ __forceinline__ unsigned short f2bf(float f) {
    unsigned u = __float_as_uint(f);
    unsigned r = 0x7fffu + ((u >> 16) & 1u);
    return (unsigned short)((u + r) >> 16);
}
__device__ __forceinline__ float bf2f(unsigned short h) {
    return __uint_as_float(((unsigned)h) << 16);
}

// async global->LDS DMA, 16 bytes per lane. LDS dest = wave-uniform base +
// lane*16 (HW rule); global source is per-lane.
__device__ __forceinline__ void gload16(const void* g, void* l) {
    __builtin_amdgcn_global_load_lds(
        (const __attribute__((address_space(1))) unsigned int*)g,
        (__attribute__((address_space(3))) unsigned int*)l, 16, 0, 0);
}

// ---------------------------------------------------------------------------
// Fused prep: weight transpose+bf16 hi/lo split (conv1, conv2, lin) + zero the
// per-destination counters. One launch.
// ---------------------------------------------------------------------------
#define PREP_W1   (8 * 65536)
#define PREP_W2   (4 * 131072)
#define PREP_WL   65536
#define PREP_CNT  (T_TYPES * N_NODES)
#define PREP_TOT  (PREP_W1 + PREP_W2 + PREP_WL + PREP_CNT)

__global__ void prep_kernel(const float* __restrict__ w1_l, const float* __restrict__ w1_r,
                            const float* __restrict__ w2_l, const float* __restrict__ w2_r,
                            const float* __restrict__ w_lin,
                            unsigned short* __restrict__ wt1h, unsigned short* __restrict__ wt1l,
                            unsigned short* __restrict__ wt2h, unsigned short* __restrict__ wt2l,
                            unsigned short* __restrict__ wtLh, unsigned short* __restrict__ wtLl,
                            int* __restrict__ count) {
    int idx = blockIdx.x * blockDim.x + threadIdx.x;
    if (idx < PREP_W1) {
        int n = idx & 255, k = (idx >> 8) & 255, mat = idx >> 16;
        int h = mat & 1, lr = (mat >> 1) & 1, t = mat >> 2;
        const float* src = lr ? w1_r : w1_l;
        float v = src[(size_t)t * 256 * 512 + (size_t)k * 512 + h * 256 + n];
        unsigned short hi = f2bf(v);
        unsigned short lo = f2bf(v - bf2f(hi));
        size_t o = (size_t)mat * 65536 + (size_t)n * 256 + k;
        wt1h[o] = hi; wt1l[o] = lo;
        return;
    }
    idx -= PREP_W1;
    if (idx < PREP_W2) {
        int n = idx & 255, k = (idx >> 8) & 511, mat = idx >> 17;
        int lr = mat & 1, t = mat >> 1;
        const float* src = lr ? w2_r : w2_l;
        float v = src[(size_t)t * 512 * 256 + (size_t)k * 256 + n];
        unsigned short hi = f2bf(v);
        unsigned short lo = f2bf(v - bf2f(hi));
        size_t o = (size_t)mat * 131072 + (size_t)n * 512 + k;
        wt2h[o] = hi; wt2l[o] = lo;
        return;
    }
    idx -= PREP_W2;
    if (idx < PREP_WL) {
        int n = idx & 255, k = idx >> 8;
        float v = w_lin[k * 256 + n];
        unsigned short hi = f2bf(v);
        unsigned short lo = f2bf(v - bf2f(hi));
        size_t o = (size_t)n * 256 + k;
        wtLh[o] = hi; wtLl[o] = lo;
        return;
    }
    idx -= PREP_WL;
    if (idx < PREP_CNT) count[idx] = 0;
}

// ---------------------------------------------------------------------------
// CSR build: histogram -> parallel 3-stage scan -> scatter.
// ---------------------------------------------------------------------------
__global__ void hist_kernel(const int* __restrict__ ei, int* __restrict__ count) {
    int idx = blockIdx.x * blockDim.x + threadIdx.x;
    if (idx >= T_TYPES * EP) return;
    int t = idx / EP, i = idx - t * EP;
    int dst = (i < E_EDGES) ? ei[t * 2 * E_EDGES + E_EDGES + i] : (i - E_EDGES);
    atomicAdd(&count[t * N_NODES + dst], 1);
}

#define SCAN_NB 30   // blocks per type, 1024 elems each (30720 >= 30000)

__global__ __launch_bounds__(256) void scan_bsum_kernel(const int* __restrict__ cnt,
                                                        int* __restrict__ bsum) {
    int t = blockIdx.y, b = blockIdx.x;
    const int* c = cnt + t * N_NODES;
    int i0 = b * 1024 + threadIdx.x * 4;
    int s = 0;
    #pragma unroll
    for (int j = 0; j < 4; ++j) { int i = i0 + j; if (i < N_NODES) s += c[i]; }
    #pragma unroll
    for (int m = 1; m < 64; m <<= 1) s += __shfl_xor(s, m);
    __shared__ int wsum[4];
    int l = threadIdx.x & 63, w = threadIdx.x >> 6;
    if (l == 0) wsum[w] = s;
    __syncthreads();
    if (threadIdx.x == 0) bsum[t * SCAN_NB + b] = wsum[0] + wsum[1] + wsum[2] + wsum[3];
}

__global__ void scan_base_kernel(int* __restrict__ bsum) {
    int t = threadIdx.x;
    if (t >= T_TYPES) return;
    int acc = 0;
    for (int b = 0; b < SCAN_NB; ++b) {
        int v = bsum[t * SCAN_NB + b];
        bsum[t * SCAN_NB + b] = acc;
        acc += v;
    }
}

__global__ __launch_bounds__(256) void scan_write_kernel(int* __restrict__ cnt,
                                                         const int* __restrict__ bsum,
                                                         int* __restrict__ off) {
    int t = blockIdx.y, b = blockIdx.x;
    int tid = threadIdx.x;
    int* c = cnt + t * N_NODES;
    int* o = off + t * (N_NODES + 1);
    int i0 = b * 1024 + tid * 4;
    int v[4]; int s = 0;
    #pragma unroll
    for (int j = 0; j < 4; ++j) { int i = i0 + j; v[j] = (i < N_NODES) ? c[i] : 0; s += v[j]; }
    __shared__ int ps[256];
    ps[tid] = s;
    __syncthreads();
    for (int ofs = 1; ofs < 256; ofs <<= 1) {
        int x = (tid >= ofs) ? ps[tid - ofs] : 0;
        __syncthreads();
        ps[tid] += x;
        __syncthreads();
    }
    int base = bsum[t * SCAN_NB + b] + ps[tid] - s;
    #pragma unroll
    for (int j = 0; j < 4; ++j) {
        int i = i0 + j;
        if (i < N_NODES) { o[i] = base; base += v[j]; c[i] = 0; }
    }
    if (b == 0 && tid == 0) o[N_NODES] = EP;
}

__global__ void scatter_kernel(const int* __restrict__ ei, const int* __restrict__ offsets,
                               int* __restrict__ cursor, int* __restrict__ csr_src) {
    int idx = blockIdx.x * blockDim.x + threadIdx.x;
    if (idx >= T_TYPES * EP) return;
    int t = idx / EP, i = idx - t * EP;
    int src, dst;
    if (i < E_EDGES) {
        src = ei[t * 2 * E_EDGES + i];
        dst = ei[t * 2 * E_EDGES + E_EDGES + i];
    } else {
        src = dst = i - E_EDGES;
    }
    int pos = offsets[t * (N_NODES + 1) + dst] + atomicAdd(&cursor[t * N_NODES + dst], 1);
    csr_src[t * EP + pos] = src;
}

// ---------------------------------------------------------------------------
// Split-precision bf16x3 MFMA GEMM, dual-output (blockIdx.y selects B/bias/C).
// Tile BM=64 x BN=256 x BK=32, 4 waves, 4x4 16x16x32 frags.
// B tiles staged via global_load_lds DMA: LDS dest linear (wave base+lane*16),
// global source chunk XOR-swizzled (m173 pattern) -> LDS holds the swizzled
// layout, b128 reads conflict-free. A: ASPLIT=0 fp32, reg-staged + in-kernel
// hi/lo split + swizzled ds_write; ASPLIT=1 pre-split bf16, gload_lds like B.
// ---------------------------------------------------------------------------
template <int ASPLIT>
__global__ __launch_bounds__(256) void gemm_mfma_kernel(
        const void* __restrict__ A0v, const void* __restrict__ A1v, int lda,
        const unsigned short* __restrict__ Bh0, const unsigned short* __restrict__ Bl0,
        const float* __restrict__ bias0, float* __restrict__ C0,
        const unsigned short* __restrict__ Bh1, const unsigned short* __restrict__ Bl1,
        const float* __restrict__ bias1, float* __restrict__ C1,
        int M, int K) {
    const unsigned short* Bh = blockIdx.y ? Bh1 : Bh0;
    const unsigned short* Bl = blockIdx.y ? Bl1 : Bl0;
    const float* bias = blockIdx.y ? bias1 : bias0;
    float* C = blockIdx.y ? C1 : C0;
    const float* Af          = (const float*)A0v;
    const unsigned short* Ah = (const unsigned short*)A0v;
    const unsigned short* Al = (const unsigned short*)A1v;

    __shared__ unsigned short Ah_s[64 * 32], Al_s[64 * 32];
    __shared__ unsigned short Bh_s[256 * 32], Bl_s[256 * 32];
    int t = threadIdx.x;
    int row0 = blockIdx.x * 64;
    int w = t >> 6;
    int l = t & 63;
    int fm = l & 15;
    int fg = l >> 4;

    f32x4 acc[4][4];
    const f32x4 zf = {0.f, 0.f, 0.f, 0.f};
    #pragma unroll
    for (int i = 0; i < 4; ++i)
        #pragma unroll
        for (int j = 0; j < 4; ++j) acc[i][j] = zf;

    int ar = t >> 3, af = t & 7;     // ASPLIT0 A staging: rows ar, ar+32
    int rs = l >> 2, cs = l & 3;     // DMA staging: row-in-span, chunk

    for (int k0 = 0; k0 < K; k0 += 32) {
        // ---- B tiles: async DMA, source chunk XOR'd so LDS = swizzled ----
        #pragma unroll
        for (int g = 0; g < 4; ++g) {
            int n = g * 64 + w * 16 + rs;
            int swn = (n >> 1) & 3;
            size_t so = (size_t)n * K + k0 + ((cs ^ swn) * 8);
            gload16(&Bh[so], &Bh_s[(g * 64 + w * 16) * 32]);
            gload16(&Bl[so], &Bl_s[(g * 64 + w * 16) * 32]);
        }
        // ---- A tile ----
        if constexpr (ASPLIT == 0) {
            #pragma unroll
            for (int v = 0; v < 2; ++v) {
                int r = v * 32 + ar;
                int rg = row0 + r;
                float4 a4 = make_float4(0.f, 0.f, 0.f, 0.f);
                if (rg < M) a4 = *(const float4*)&Af[(size_t)rg * lda + k0 + af * 4];
                ushort4 hi, lo;
                hi.x = f2bf(a4.x); lo.x = f2bf(a4.x - bf2f(hi.x));
                hi.y = f2bf(a4.y); lo.y = f2bf(a4.y - bf2f(hi.y));
                hi.z = f2bf(a4.z); lo.z = f2bf(a4.z - bf2f(hi.z));
                hi.w = f2bf(a4.w); lo.w = f2bf(a4.w - bf2f(hi.w));
                int ke = (af * 4) ^ (((r >> 1) & 3) << 3);
                *(ushort4*)&Ah_s[r * 32 + ke] = hi;
                *(ushort4*)&Al_s[r * 32 + ke] = lo;
            }
        } else {
            int r = w * 16 + rs;
            int rg = row0 + r;
            if (rg >= M) rg = M - 1;            // clamp: garbage rows masked at store
            int swn = (r >> 1) & 3;
            size_t so = (size_t)rg * lda + k0 + ((cs ^ swn) * 8);
            gload16(&Ah[so], &Ah_s[(w * 16) * 32]);
            gload16(&Al[so], &Al_s[(w * 16) * 32]);
        }
        __syncthreads();   // compiler drains vmcnt (DMA) + lgkmcnt here
        // ---- fragments (swizzled reads, conflict-free) ----
        bf16x8 ahf[4], alf[4], bhf[4], blf[4];
        #pragma unroll
        for (int i = 0; i < 4; ++i) {
            int r = i * 16 + fm;
            int ke = (fg * 8) ^ (((r >> 1) & 3) << 3);
            ahf[i] = *(const bf16x8*)&Ah_s[r * 32 + ke];
            alf[i] = *(const bf16x8*)&Al_s[r * 32 + ke];
        }
        #pragma unroll
        for (int j = 0; j < 4; ++j) {
            int n = w * 64 + j * 16 + fm;
            int ke = (fg * 8) ^ (((n >> 1) & 3) << 3);
            bhf[j] = *(const bf16x8*)&Bh_s[n * 32 + ke];
            blf[j] = *(const bf16x8*)&Bl_s[n * 32 + ke];
        }
        #pragma unroll
        for (int i = 0; i < 4; ++i)
            #pragma unroll
            for (int j = 0; j < 4; ++j) {
                acc[i][j] = __builtin_amdgcn_mfma_f32_16x16x32_bf16(ahf[i], bhf[j], acc[i][j], 0, 0, 0);
                acc[i][j] = __builtin_amdgcn_mfma_f32_16x16x32_bf16(ahf[i], blf[j], acc[i][j], 0, 0, 0);
                acc[i][j] = __builtin_amdgcn_mfma_f32_16x16x32_bf16(alf[i], bhf[j], acc[i][j], 0, 0, 0);
            }
        __syncthreads();
    }
    // ---- epilogue (C/D map: col=lane&15, row=(lane>>4)*4+q) ----
    #pragma unroll
    for (int j = 0; j < 4; ++j) {
        int col = w * 64 + j * 16 + fm;
        float bv = bias[col];
        #pragma unroll
        for (int i = 0; i < 4; ++i) {
            #pragma unroll
            for (int q = 0; q < 4; ++q) {
                int rg = row0 + i * 16 + fg * 4 + q;
                if (rg < M) C[(size_t)rg * 256 + col] = acc[i][j][q] + bv;
            }
        }
    }
}

// ---------------------------------------------------------------------------
// Fused GATv2 edge kernel over a 256-column block. One wave per destination.
// MODE 0: out = result (fp32).
// MODE 2: out = elu(out + result + eb0 + eb1)  (fp32).
// MODE 3: v = elu(out + result + eb0 + eb1); write bf16 hi/lo split to sh/sl.
// ---------------------------------------------------------------------------
template <int RW, int MODE>
__global__ __launch_bounds__(256) void gat_edge_kernel(
        const float* __restrict__ xl, const float* __restrict__ xr,
        const float* __restrict__ att,
        const int* __restrict__ offs, const int* __restrict__ csr,
        float* __restrict__ out, int ldo,
        const float* __restrict__ eb0, const float* __restrict__ eb1,
        unsigned short* __restrict__ sh, unsigned short* __restrict__ sl) {
    int wave = (blockIdx.x * blockDim.x + threadIdx.x) >> 6;
    int lane = threadIdx.x & 63;
    if (wave >= N_NODES) return;
    int d = wave;
    int q4 = lane * 4;
    float attr[4], xrr[4];
    *(float4*)&attr[0] = *(const float4*)&att[q4];
    *(float4*)&xrr[0]  = *(const float4*)&xr[(size_t)d * 256 + q4];
    float m = -INFINITY, s = 0.f;
    float acc[4] = {0.f, 0.f, 0.f, 0.f};
    int p0 = offs[d], p1 = offs[d + 1];
    int p = p0;
    for (; p + 2 <= p1; p += 2) {
        int s0 = csr[p], s1 = csr[p + 1];
        float xv0[4], xv1[4];
        *(float4*)&xv0[0] = *(const float4*)&xl[(size_t)s0 * 256 + q4];
        *(float4*)&xv1[0] = *(const float4*)&xl[(size_t)s1 * 256 + q4];
        float e0 = 0.f, e1 = 0.f;
        #pragma unroll
        for (int q = 0; q < 4; ++q) {
            float h0 = xv0[q] + xrr[q];
            float h1 = xv1[q] + xrr[q];
            h0 = (h0 > 0.f) ? h0 : 0.2f * h0;
            h1 = (h1 > 0.f) ? h1 : 0.2f * h1;
            e0 += attr[q] * h0;
            e1 += attr[q] * h1;
        }
        #pragma unroll
        for (int msk = 1; msk < RW; msk <<= 1) {
            e0 += __shfl_xor(e0, msk);
            e1 += __shfl_xor(e1, msk);
        }
        float mn = fmaxf(m, e0);
        float sc = __expf(m - mn);
        float pe = __expf(e0 - mn);
        s = s * sc + pe;
        #pragma unroll
        for (int q = 0; q < 4; ++q) acc[q] = acc[q] * sc + pe * xv0[q];
        m = mn;
        mn = fmaxf(m, e1);
        sc = __expf(m - mn);
        pe = __expf(e1 - mn);
        s = s * sc + pe;
        #pragma unroll
        for (int q = 0; q < 4; ++q) acc[q] = acc[q] * sc + pe * xv1[q];
        m = mn;
    }
    if (p < p1) {
        int s0 = csr[p];
        float xv0[4];
        *(float4*)&xv0[0] = *(const float4*)&xl[(size_t)s0 * 256 + q4];
        float e0 = 0.f;
        #pragma unroll
        for (int q = 0; q < 4; ++q) {
            float h0 = xv0[q] + xrr[q];
            h0 = (h0 > 0.f) ? h0 : 0.2f * h0;
            e0 += attr[q] * h0;
        }
        #pragma unroll
        for (int msk = 1; msk < RW; msk <<= 1) e0 += __shfl_xor(e0, msk);
        float mn = fmaxf(m, e0);
        float sc = __expf(m - mn);
        float pe = __expf(e0 - mn);
        s = s * sc + pe;
        #pragma unroll
        for (int q = 0; q < 4; ++q) acc[q] = acc[q] * sc + pe * xv0[q];
        m = mn;
    }
    float inv = 1.f / s;
    float* dp = &out[(size_t)d * ldo + q4];
    if (MODE == 0) {
        *(float4*)dp = make_float4(acc[0] * inv, acc[1] * inv, acc[2] * inv, acc[3] * inv);
    } else if (MODE == 2) {
        #pragma unroll
        for (int q = 0; q < 4; ++q) {
            float v = dp[q] + acc[q] * inv + eb0[q4 + q] + eb1[q4 + q];
            dp[q] = (v > 0.f) ? v : (__expf(v) - 1.f);
        }
    } else {   // MODE 3: elu + bf16 hi/lo split write
        ushort4 hv, lv;
        float v0 = dp[0] + acc[0] * inv + eb0[q4 + 0] + eb1[q4 + 0];
        float v1 = dp[1] + acc[1] * inv + eb0[q4 + 1] + eb1[q4 + 1];
        float v2 = dp[2] + acc[2] * inv + eb0[q4 + 2] + eb1[q4 + 2];
        float v3 = dp[3] + acc[3] * inv + eb0[q4 + 3] + eb1[q4 + 3];
        v0 = (v0 > 0.f) ? v0 : (__expf(v0) - 1.f);
        v1 = (v1 > 0.f) ? v1 : (__expf(v1) - 1.f);
        v2 = (v2 > 0.f) ? v2 : (__expf(v2) - 1.f);
        v3 = (v3 > 0.f) ? v3 : (__expf(v3) - 1.f);
        hv.x = f2bf(v0); lv.x = f2bf(v0 - bf2f(hv.x));
        hv.y = f2bf(v1); lv.y = f2bf(v1 - bf2f(hv.y));
        hv.z = f2bf(v2); lv.z = f2bf(v2 - bf2f(hv.z));
        hv.w = f2bf(v3); lv.w = f2bf(v3 - bf2f(hv.w));
        *(ushort4*)&sh[(size_t)d * ldo + q4] = hv;
        *(ushort4*)&sl[(size_t)d * ldo + q4] = lv;
    }
}

// ---------------------------------------------------------------------------
extern "C" void kernel_launch(void* const* d_in, const int* in_sizes, int n_in,
                              void* d_out, int out_size, void* d_ws, size_t ws_size,
                              hipStream_t stream) {
    const float* x      = (const float*)d_in[0];
    const int*   ei     = (const int*)d_in[1];
    const float* w1_l   = (const float*)d_in[2];
    const float* b1_l   = (const float*)d_in[3];
    const float* w1_r   = (const float*)d_in[4];
    const float* b1_r   = (const float*)d_in[5];
    const float* att1   = (const float*)d_in[6];
    const float* bias1  = (const float*)d_in[7];
    const float* w2_l   = (const float*)d_in[8];
    const float* b2_l   = (const float*)d_in[9];
    const float* w2_r   = (const float*)d_in[10];
    const float* b2_r   = (const float*)d_in[11];
    const float* att2   = (const float*)d_in[12];
    const float* bias2  = (const float*)d_in[13];
    const float* w_lin  = (const float*)d_in[14];
    const float* b_lin  = (const float*)d_in[15];
    float* out = (float*)d_out;

    // ---- workspace layout (~130 MB) ----
    float* h1   = (float*)d_ws;                        // [N][512]  61.44 MB
    float* bufA = h1 + (size_t)N_NODES * F1;           // [N][256]  30.72 MB
    float* bufB = bufA + (size_t)N_NODES * OUT_F;      // [N][256]  30.72 MB
    unsigned short* wt1h = (unsigned short*)(bufB + (size_t)N_NODES * OUT_F);
    unsigned short* wt1l = wt1h + 8 * 65536;
    unsigned short* wt2h = wt1l + 8 * 65536;
    unsigned short* wt2l = wt2h + 4 * 131072;
    unsigned short* wtLh = wt2l + 4 * 131072;
    unsigned short* wtLl = wtLh + 65536;
    int* count   = (int*)(wtLl + 65536);
    int* offsets = count + T_TYPES * N_NODES;
    int* bsum    = offsets + T_TYPES * (N_NODES + 1);
    int* csr     = bsum + T_TYPES * SCAN_NB;
    // h2 split overlays h1's storage (h1 fp32 is dead once conv2 GEMMs read it)
    unsigned short* h2s_hi = (unsigned short*)h1;
    unsigned short* h2s_lo = h2s_hi + (size_t)N_NODES * OUT_F;

    // --- prep (weights split + count zero) ---
    prep_kernel<<<(PREP_TOT + 255) / 256, 256, 0, stream>>>(
        w1_l, w1_r, w2_l, w2_r, w_lin, wt1h, wt1l, wt2h, wt2l, wtLh, wtLl, count);

    // --- build CSR (by dst), shared by both convs ---
    int eblocks = (T_TYPES * EP + 255) / 256;
    hist_kernel<<<eblocks, 256, 0, stream>>>(ei, count);
    dim3 sgrid(SCAN_NB, T_TYPES);
    scan_bsum_kernel<<<sgrid, 256, 0, stream>>>(count, bsum);
    scan_base_kernel<<<1, 64, 0, stream>>>(bsum);
    scan_write_kernel<<<sgrid, 256, 0, stream>>>(count, bsum, offsets);
    scatter_kernel<<<eblocks, 256, 0, stream>>>(ei, offsets, count, csr);

    int gat_blocks = N_NODES / 4;
    dim3 ggrid((N_NODES + 63) / 64, 2);   // dual-output GEMM
    dim3 ggrid1((N_NODES + 63) / 64, 1);  // single-output GEMM

    // --- conv1: per (t, head-half): l+r GEMMs in one launch, then edge kernel ---
    for (int t = 0; t < T_TYPES; ++t) {
        for (int hh = 0; hh < 2; ++hh) {
            int co = hh * 256;
            int ml = (t * 2 + 0) * 2 + hh, mr = (t * 2 + 1) * 2 + hh;
            gemm_mfma_kernel<0><<<ggrid, 256, 0, stream>>>(
                x, nullptr, D_IN,
                wt1h + (size_t)ml * 65536, wt1l + (size_t)ml * 65536, b1_l + t * F1 + co, bufA,
                wt1h + (size_t)mr * 65536, wt1l + (size_t)mr * 65536, b1_r + t * F1 + co, bufB,
                N_NODES, D_IN);
            if (t == 0)
                gat_edge_kernel<16, 0><<<gat_blocks, 256, 0, stream>>>(
                    bufA, bufB, att1 + t * F1 + co, offsets + t * (N_NODES + 1),
                    csr + (size_t)t * EP, h1 + co, F1, nullptr, nullptr, nullptr, nullptr);
            else
                gat_edge_kernel<16, 2><<<gat_blocks, 256, 0, stream>>>(
                    bufA, bufB, att1 + t * F1 + co, offsets + t * (N_NODES + 1),
                    csr + (size_t)t * EP, h1 + co, F1, bias1 + co, bias1 + F1 + co,
                    nullptr, nullptr);
        }
    }

    // --- conv2 (1 head, 256 cols); t1 edge writes pre-split h2 ---
    for (int t = 0; t < T_TYPES; ++t) {
        int ml = t * 2 + 0, mr = t * 2 + 1;
        gemm_mfma_kernel<0><<<ggrid, 256, 0, stream>>>(
            h1, nullptr, F1,
            wt2h + (size_t)ml * 131072, wt2l + (size_t)ml * 131072, b2_l + t * OUT_F, bufA,
            wt2h + (size_t)mr * 131072, wt2l + (size_t)mr * 131072, b2_r + t * OUT_F, bufB,
            N_NODES, F1);
        if (t == 0)
            gat_edge_kernel<64, 0><<<gat_blocks, 256, 0, stream>>>(
                bufA, bufB, att2 + t * OUT_F, offsets + t * (N_NODES + 1),
                csr + (size_t)t * EP, out, OUT_F, nullptr, nullptr, nullptr, nullptr);
        else
            gat_edge_kernel<64, 3><<<gat_blocks, 256, 0, stream>>>(
                bufA, bufB, att2 + t * OUT_F, offsets + t * (N_NODES + 1),
                csr + (size_t)t * EP, out, OUT_F, bias2, bias2 + OUT_F,
                h2s_hi, h2s_lo);
    }

    // --- final linear: reads pre-split h2 via DMA path, writes d_out ---
    gemm_mfma_kernel<1><<<ggrid1, 256, 0, stream>>>(
        h2s_hi, h2s_lo, OUT_F,
        wtLh, wtLl, b_lin, out,
        wtLh, wtLl, b_lin, out,
        N_NODES, OUT_F);
}

// Round 11
// 862.849 us; speedup vs baseline: 1.7151x; 1.0342x over previous
//
#include <hip/hip_runtime.h>
#include <math.h>

#define N_NODES 30000
#define D_IN    256
#define E_EDGES 300000
#define T_TYPES 2
#define HEADS   8
#define HID     64
#define F1      512   // HEADS*HID
#define OUT_F   256
#define EP      (E_EDGES + N_NODES)   // 330000 edges per type incl self-loops

typedef __attribute__((ext_vector_type(8))) short bf16x8;
typedef __attribute__((ext_vector_type(4))) float f32x4;

__device__ __forceinline__ unsigned short f2bf(float f) {
    unsigned u = __float_as_uint(f);
    unsigned r = 0x7fffu + ((u >> 16) & 1u);
    return (unsigned short)((u + r) >> 16);
}
__device__ __forceinline__ float bf2f(unsigned short h) {
    return __uint_as_float(((unsigned)h) << 16);
}

// async global->LDS DMA, 16 bytes per lane. LDS dest = wave-uniform base +
// lane*16 (HW rule); global source is per-lane.
__device__ __forceinline__ void gload16(const void* g, void* l) {
    __builtin_amdgcn_global_load_lds(
        (const __attribute__((address_space(1))) unsigned int*)g,
        (__attribute__((address_space(3))) unsigned int*)l, 16, 0, 0);
}

// ---------------------------------------------------------------------------
// Fused prep: weight transpose+bf16 hi/lo split (conv1, conv2, lin) + zero the
// per-destination counters. One launch.
// ---------------------------------------------------------------------------
#define PREP_W1   (8 * 65536)
#define PREP_W2   (4 * 131072)
#define PREP_WL   65536
#define PREP_CNT  (T_TYPES * N_NODES)
#define PREP_TOT  (PREP_W1 + PREP_W2 + PREP_WL + PREP_CNT)

__global__ void prep_kernel(const float* __restrict__ w1_l, const float* __restrict__ w1_r,
                            const float* __restrict__ w2_l, const float* __restrict__ w2_r,
                            const float* __restrict__ w_lin,
                            unsigned short* __restrict__ wt1h, unsigned short* __restrict__ wt1l,
                            unsigned short* __restrict__ wt2h, unsigned short* __restrict__ wt2l,
                            unsigned short* __restrict__ wtLh, unsigned short* __restrict__ wtLl,
                            int* __restrict__ count) {
    int idx = blockIdx.x * blockDim.x + threadIdx.x;
    if (idx < PREP_W1) {
        int n = idx & 255, k = (idx >> 8) & 255, mat = idx >> 16;
        int h = mat & 1, lr = (mat >> 1) & 1, t = mat >> 2;
        const float* src = lr ? w1_r : w1_l;
        float v = src[(size_t)t * 256 * 512 + (size_t)k * 512 + h * 256 + n];
        unsigned short hi = f2bf(v);
        unsigned short lo = f2bf(v - bf2f(hi));
        size_t o = (size_t)mat * 65536 + (size_t)n * 256 + k;
        wt1h[o] = hi; wt1l[o] = lo;
        return;
    }
    idx -= PREP_W1;
    if (idx < PREP_W2) {
        int n = idx & 255, k = (idx >> 8) & 511, mat = idx >> 17;
        int lr = mat & 1, t = mat >> 1;
        const float* src = lr ? w2_r : w2_l;
        float v = src[(size_t)t * 512 * 256 + (size_t)k * 256 + n];
        unsigned short hi = f2bf(v);
        unsigned short lo = f2bf(v - bf2f(hi));
        size_t o = (size_t)mat * 131072 + (size_t)n * 512 + k;
        wt2h[o] = hi; wt2l[o] = lo;
        return;
    }
    idx -= PREP_W2;
    if (idx < PREP_WL) {
        int n = idx & 255, k = idx >> 8;
        float v = w_lin[k * 256 + n];
        unsigned short hi = f2bf(v);
        unsigned short lo = f2bf(v - bf2f(hi));
        size_t o = (size_t)n * 256 + k;
        wtLh[o] = hi; wtLl[o] = lo;
        return;
    }
    idx -= PREP_WL;
    if (idx < PREP_CNT) count[idx] = 0;
}

// ---------------------------------------------------------------------------
// CSR build: histogram -> parallel 3-stage scan -> scatter.
// ---------------------------------------------------------------------------
__global__ void hist_kernel(const int* __restrict__ ei, int* __restrict__ count) {
    int idx = blockIdx.x * blockDim.x + threadIdx.x;
    if (idx >= T_TYPES * EP) return;
    int t = idx / EP, i = idx - t * EP;
    int dst = (i < E_EDGES) ? ei[t * 2 * E_EDGES + E_EDGES + i] : (i - E_EDGES);
    atomicAdd(&count[t * N_NODES + dst], 1);
}

#define SCAN_NB 30   // blocks per type, 1024 elems each (30720 >= 30000)

__global__ __launch_bounds__(256) void scan_bsum_kernel(const int* __restrict__ cnt,
                                                        int* __restrict__ bsum) {
    int t = blockIdx.y, b = blockIdx.x;
    const int* c = cnt + t * N_NODES;
    int i0 = b * 1024 + threadIdx.x * 4;
    int s = 0;
    #pragma unroll
    for (int j = 0; j < 4; ++j) { int i = i0 + j; if (i < N_NODES) s += c[i]; }
    #pragma unroll
    for (int m = 1; m < 64; m <<= 1) s += __shfl_xor(s, m);
    __shared__ int wsum[4];
    int l = threadIdx.x & 63, w = threadIdx.x >> 6;
    if (l == 0) wsum[w] = s;
    __syncthreads();
    if (threadIdx.x == 0) bsum[t * SCAN_NB + b] = wsum[0] + wsum[1] + wsum[2] + wsum[3];
}

__global__ void scan_base_kernel(int* __restrict__ bsum) {
    int t = threadIdx.x;
    if (t >= T_TYPES) return;
    int acc = 0;
    for (int b = 0; b < SCAN_NB; ++b) {
        int v = bsum[t * SCAN_NB + b];
        bsum[t * SCAN_NB + b] = acc;
        acc += v;
    }
}

__global__ __launch_bounds__(256) void scan_write_kernel(int* __restrict__ cnt,
                                                         const int* __restrict__ bsum,
                                                         int* __restrict__ off) {
    int t = blockIdx.y, b = blockIdx.x;
    int tid = threadIdx.x;
    int* c = cnt + t * N_NODES;
    int* o = off + t * (N_NODES + 1);
    int i0 = b * 1024 + tid * 4;
    int v[4]; int s = 0;
    #pragma unroll
    for (int j = 0; j < 4; ++j) { int i = i0 + j; v[j] = (i < N_NODES) ? c[i] : 0; s += v[j]; }
    __shared__ int ps[256];
    ps[tid] = s;
    __syncthreads();
    for (int ofs = 1; ofs < 256; ofs <<= 1) {
        int x = (tid >= ofs) ? ps[tid - ofs] : 0;
        __syncthreads();
        ps[tid] += x;
        __syncthreads();
    }
    int base = bsum[t * SCAN_NB + b] + ps[tid] - s;
    #pragma unroll
    for (int j = 0; j < 4; ++j) {
        int i = i0 + j;
        if (i < N_NODES) { o[i] = base; base += v[j]; c[i] = 0; }
    }
    if (b == 0 && tid == 0) o[N_NODES] = EP;
}

__global__ void scatter_kernel(const int* __restrict__ ei, const int* __restrict__ offsets,
                               int* __restrict__ cursor, int* __restrict__ csr_src) {
    int idx = blockIdx.x * blockDim.x + threadIdx.x;
    if (idx >= T_TYPES * EP) return;
    int t = idx / EP, i = idx - t * EP;
    int src, dst;
    if (i < E_EDGES) {
        src = ei[t * 2 * E_EDGES + i];
        dst = ei[t * 2 * E_EDGES + E_EDGES + i];
    } else {
        src = dst = i - E_EDGES;
    }
    int pos = offsets[t * (N_NODES + 1) + dst] + atomicAdd(&cursor[t * N_NODES + dst], 1);
    csr_src[t * EP + pos] = src;
}

// ---------------------------------------------------------------------------
// Split-precision bf16x3 MFMA GEMM, dual-output (blockIdx.y selects B/bias/C).
// Tile BM=64 x BN=256 x BK=32, 4 waves, 4x4 16x16x32 frags.
// DOUBLE-BUFFERED, ONE barrier per K-step: iteration i stages tile i+1 into
// buf[nxt] (B via global_load_lds DMA with pre-swizzled source; A via regs
// prefetched one iter earlier -> cvt -> swizzled ds_write), then computes
// tile i from buf[cur], then a single __syncthreads (vmcnt/lgkm drain) --
// the staging latency hides under the ds_read+MFMA phase.
// ---------------------------------------------------------------------------
#define STAGE_B(BUF, K0)                                                     \
    do {                                                                     \
        _Pragma("unroll")                                                    \
        for (int g = 0; g < 4; ++g) {                                        \
            int n_ = g * 64 + w * 16 + rs;                                   \
            int swn_ = (n_ >> 1) & 3;                                        \
            size_t so_ = (size_t)n_ * K + (K0) + ((cs ^ swn_) * 8);          \
            gload16(&Bh[so_], &Bh_s[BUF][(g * 64 + w * 16) * 32]);           \
            gload16(&Bl[so_], &Bl_s[BUF][(g * 64 + w * 16) * 32]);           \
        }                                                                    \
    } while (0)

#define STAGE_A_DMA(BUF, K0)                                                 \
    do {                                                                     \
        int r_ = w * 16 + rs;                                                \
        int rg_ = row0 + r_;                                                 \
        if (rg_ >= M) rg_ = M - 1;                                           \
        int swn_ = (r_ >> 1) & 3;                                            \
        size_t so_ = (size_t)rg_ * lda + (K0) + ((cs ^ swn_) * 8);           \
        gload16(&Ah[so_], &Ah_s[BUF][(w * 16) * 32]);                        \
        gload16(&Al[so_], &Al_s[BUF][(w * 16) * 32]);                        \
    } while (0)

#define LOAD_A_REGS(K0)                                                      \
    do {                                                                     \
        int rg0_ = row0 + ar;                                                \
        int rg1_ = row0 + 32 + ar;                                           \
        aN0 = (rg0_ < M) ? *(const float4*)&Af[(size_t)rg0_ * lda + (K0) + af * 4] \
                         : make_float4(0.f, 0.f, 0.f, 0.f);                  \
        aN1 = (rg1_ < M) ? *(const float4*)&Af[(size_t)rg1_ * lda + (K0) + af * 4] \
                         : make_float4(0.f, 0.f, 0.f, 0.f);                  \
    } while (0)

#define WRITE_A(BUF)                                                         \
    do {                                                                     \
        ushort4 hi_, lo_;                                                    \
        int r_ = ar;                                                         \
        hi_.x = f2bf(aN0.x); lo_.x = f2bf(aN0.x - bf2f(hi_.x));              \
        hi_.y = f2bf(aN0.y); lo_.y = f2bf(aN0.y - bf2f(hi_.y));              \
        hi_.z = f2bf(aN0.z); lo_.z = f2bf(aN0.z - bf2f(hi_.z));              \
        hi_.w = f2bf(aN0.w); lo_.w = f2bf(aN0.w - bf2f(hi_.w));              \
        int ke_ = (af * 4) ^ (((r_ >> 1) & 3) << 3);                         \
        *(ushort4*)&Ah_s[BUF][r_ * 32 + ke_] = hi_;                          \
        *(ushort4*)&Al_s[BUF][r_ * 32 + ke_] = lo_;                          \
        r_ = 32 + ar;                                                        \
        hi_.x = f2bf(aN1.x); lo_.x = f2bf(aN1.x - bf2f(hi_.x));              \
        hi_.y = f2bf(aN1.y); lo_.y = f2bf(aN1.y - bf2f(hi_.y));              \
        hi_.z = f2bf(aN1.z); lo_.z = f2bf(aN1.z - bf2f(hi_.z));              \
        hi_.w = f2bf(aN1.w); lo_.w = f2bf(aN1.w - bf2f(hi_.w));              \
        ke_ = (af * 4) ^ (((r_ >> 1) & 3) << 3);                             \
        *(ushort4*)&Ah_s[BUF][r_ * 32 + ke_] = hi_;                          \
        *(ushort4*)&Al_s[BUF][r_ * 32 + ke_] = lo_;                          \
    } while (0)

template <int ASPLIT>
__global__ __launch_bounds__(256) void gemm_mfma_kernel(
        const void* __restrict__ A0v, const void* __restrict__ A1v, int lda,
        const unsigned short* __restrict__ Bh0, const unsigned short* __restrict__ Bl0,
        const float* __restrict__ bias0, float* __restrict__ C0,
        const unsigned short* __restrict__ Bh1, const unsigned short* __restrict__ Bl1,
        const float* __restrict__ bias1, float* __restrict__ C1,
        int M, int K) {
    const unsigned short* Bh = blockIdx.y ? Bh1 : Bh0;
    const unsigned short* Bl = blockIdx.y ? Bl1 : Bl0;
    const float* bias = blockIdx.y ? bias1 : bias0;
    float* C = blockIdx.y ? C1 : C0;
    const float* Af          = (const float*)A0v;
    const unsigned short* Ah = (const unsigned short*)A0v;
    const unsigned short* Al = (const unsigned short*)A1v;

    __shared__ unsigned short Ah_s[2][64 * 32], Al_s[2][64 * 32];
    __shared__ unsigned short Bh_s[2][256 * 32], Bl_s[2][256 * 32];
    int t = threadIdx.x;
    int row0 = blockIdx.x * 64;
    int w = t >> 6;
    int l = t & 63;
    int fm = l & 15;
    int fg = l >> 4;

    f32x4 acc[4][4];
    const f32x4 zf = {0.f, 0.f, 0.f, 0.f};
    #pragma unroll
    for (int i = 0; i < 4; ++i)
        #pragma unroll
        for (int j = 0; j < 4; ++j) acc[i][j] = zf;

    int ar = t >> 3, af = t & 7;     // ASPLIT0 A staging: rows ar, ar+32
    int rs = l >> 2, cs = l & 3;     // DMA staging: row-in-span, chunk

    float4 aN0, aN1;                 // A prefetch regs (named, never arrays)
    int nk = K >> 5;

    // ---- prologue: stage tile 0 into buf 0; prefetch A regs for tile 1 ----
    if constexpr (ASPLIT == 0) {
        LOAD_A_REGS(0);
        STAGE_B(0, 0);
        WRITE_A(0);                       // counted vmcnt wait on aN only
        if (nk > 1) LOAD_A_REGS(32);
    } else {
        STAGE_B(0, 0);
        STAGE_A_DMA(0, 0);
    }
    __syncthreads();

    for (int i = 0; i < nk; ++i) {
        int cur = i & 1, nxt = cur ^ 1;
        // ---- stage tile i+1 into buf[nxt] (overlaps with compute below) ----
        if (i + 1 < nk) {
            int k1 = (i + 1) << 5;
            STAGE_B(nxt, k1);
            if constexpr (ASPLIT == 0) {
                WRITE_A(nxt);             // regs hold tile i+1 (loaded iter i-1)
                if (i + 2 < nk) LOAD_A_REGS(k1 + 32);
            } else {
                STAGE_A_DMA(nxt, k1);
            }
        }
        // ---- compute tile i from buf[cur] ----
        bf16x8 ahf[4], alf[4], bhf[4], blf[4];
        #pragma unroll
        for (int ii = 0; ii < 4; ++ii) {
            int r = ii * 16 + fm;
            int ke = (fg * 8) ^ (((r >> 1) & 3) << 3);
            ahf[ii] = *(const bf16x8*)&Ah_s[cur][r * 32 + ke];
            alf[ii] = *(const bf16x8*)&Al_s[cur][r * 32 + ke];
        }
        #pragma unroll
        for (int j = 0; j < 4; ++j) {
            int n = w * 64 + j * 16 + fm;
            int ke = (fg * 8) ^ (((n >> 1) & 3) << 3);
            bhf[j] = *(const bf16x8*)&Bh_s[cur][n * 32 + ke];
            blf[j] = *(const bf16x8*)&Bl_s[cur][n * 32 + ke];
        }
        #pragma unroll
        for (int ii = 0; ii < 4; ++ii)
            #pragma unroll
            for (int j = 0; j < 4; ++j) {
                acc[ii][j] = __builtin_amdgcn_mfma_f32_16x16x32_bf16(ahf[ii], bhf[j], acc[ii][j], 0, 0, 0);
                acc[ii][j] = __builtin_amdgcn_mfma_f32_16x16x32_bf16(ahf[ii], blf[j], acc[ii][j], 0, 0, 0);
                acc[ii][j] = __builtin_amdgcn_mfma_f32_16x16x32_bf16(alf[ii], bhf[j], acc[ii][j], 0, 0, 0);
            }
        __syncthreads();   // single barrier: drains DMA+A-loads, guards buf reuse
    }
    // ---- epilogue (C/D map: col=lane&15, row=(lane>>4)*4+q) ----
    #pragma unroll
    for (int j = 0; j < 4; ++j) {
        int col = w * 64 + j * 16 + fm;
        float bv = bias[col];
        #pragma unroll
        for (int i = 0; i < 4; ++i) {
            #pragma unroll
            for (int q = 0; q < 4; ++q) {
                int rg = row0 + i * 16 + fg * 4 + q;
                if (rg < M) C[(size_t)rg * 256 + col] = acc[i][j][q] + bv;
            }
        }
    }
}

// ---------------------------------------------------------------------------
// Fused GATv2 edge kernel over a 256-column block. One wave per destination.
// MODE 0: out = result (fp32).
// MODE 2: out = elu(out + result + eb0 + eb1)  (fp32).
// MODE 3: v = elu(out + result + eb0 + eb1); write bf16 hi/lo split to sh/sl.
// ---------------------------------------------------------------------------
template <int RW, int MODE>
__global__ __launch_bounds__(256) void gat_edge_kernel(
        const float* __restrict__ xl, const float* __restrict__ xr,
        const float* __restrict__ att,
        const int* __restrict__ offs, const int* __restrict__ csr,
        float* __restrict__ out, int ldo,
        const float* __restrict__ eb0, const float* __restrict__ eb1,
        unsigned short* __restrict__ sh, unsigned short* __restrict__ sl) {
    int wave = (blockIdx.x * blockDim.x + threadIdx.x) >> 6;
    int lane = threadIdx.x & 63;
    if (wave >= N_NODES) return;
    int d = wave;
    int q4 = lane * 4;
    float attr[4], xrr[4];
    *(float4*)&attr[0] = *(const float4*)&att[q4];
    *(float4*)&xrr[0]  = *(const float4*)&xr[(size_t)d * 256 + q4];
    float m = -INFINITY, s = 0.f;
    float acc[4] = {0.f, 0.f, 0.f, 0.f};
    int p0 = offs[d], p1 = offs[d + 1];
    int p = p0;
    for (; p + 2 <= p1; p += 2) {
        int s0 = csr[p], s1 = csr[p + 1];
        float xv0[4], xv1[4];
        *(float4*)&xv0[0] = *(const float4*)&xl[(size_t)s0 * 256 + q4];
        *(float4*)&xv1[0] = *(const float4*)&xl[(size_t)s1 * 256 + q4];
        float e0 = 0.f, e1 = 0.f;
        #pragma unroll
        for (int q = 0; q < 4; ++q) {
            float h0 = xv0[q] + xrr[q];
            float h1 = xv1[q] + xrr[q];
            h0 = (h0 > 0.f) ? h0 : 0.2f * h0;
            h1 = (h1 > 0.f) ? h1 : 0.2f * h1;
            e0 += attr[q] * h0;
            e1 += attr[q] * h1;
        }
        #pragma unroll
        for (int msk = 1; msk < RW; msk <<= 1) {
            e0 += __shfl_xor(e0, msk);
            e1 += __shfl_xor(e1, msk);
        }
        float mn = fmaxf(m, e0);
        float sc = __expf(m - mn);
        float pe = __expf(e0 - mn);
        s = s * sc + pe;
        #pragma unroll
        for (int q = 0; q < 4; ++q) acc[q] = acc[q] * sc + pe * xv0[q];
        m = mn;
        mn = fmaxf(m, e1);
        sc = __expf(m - mn);
        pe = __expf(e1 - mn);
        s = s * sc + pe;
        #pragma unroll
        for (int q = 0; q < 4; ++q) acc[q] = acc[q] * sc + pe * xv1[q];
        m = mn;
    }
    if (p < p1) {
        int s0 = csr[p];
        float xv0[4];
        *(float4*)&xv0[0] = *(const float4*)&xl[(size_t)s0 * 256 + q4];
        float e0 = 0.f;
        #pragma unroll
        for (int q = 0; q < 4; ++q) {
            float h0 = xv0[q] + xrr[q];
            h0 = (h0 > 0.f) ? h0 : 0.2f * h0;
            e0 += attr[q] * h0;
        }
        #pragma unroll
        for (int msk = 1; msk < RW; msk <<= 1) e0 += __shfl_xor(e0, msk);
        float mn = fmaxf(m, e0);
        float sc = __expf(m - mn);
        float pe = __expf(e0 - mn);
        s = s * sc + pe;
        #pragma unroll
        for (int q = 0; q < 4; ++q) acc[q] = acc[q] * sc + pe * xv0[q];
        m = mn;
    }
    float inv = 1.f / s;
    float* dp = &out[(size_t)d * ldo + q4];
    if (MODE == 0) {
        *(float4*)dp = make_float4(acc[0] * inv, acc[1] * inv, acc[2] * inv, acc[3] * inv);
    } else if (MODE == 2) {
        #pragma unroll
        for (int q = 0; q < 4; ++q) {
            float v = dp[q] + acc[q] * inv + eb0[q4 + q] + eb1[q4 + q];
            dp[q] = (v > 0.f) ? v : (__expf(v) - 1.f);
        }
    } else {   // MODE 3: elu + bf16 hi/lo split write
        ushort4 hv, lv;
        float v0 = dp[0] + acc[0] * inv + eb0[q4 + 0] + eb1[q4 + 0];
        float v1 = dp[1] + acc[1] * inv + eb0[q4 + 1] + eb1[q4 + 1];
        float v2 = dp[2] + acc[2] * inv + eb0[q4 + 2] + eb1[q4 + 2];
        float v3 = dp[3] + acc[3] * inv + eb0[q4 + 3] + eb1[q4 + 3];
        v0 = (v0 > 0.f) ? v0 : (__expf(v0) - 1.f);
        v1 = (v1 > 0.f) ? v1 : (__expf(v1) - 1.f);
        v2 = (v2 > 0.f) ? v2 : (__expf(v2) - 1.f);
        v3 = (v3 > 0.f) ? v3 : (__expf(v3) - 1.f);
        hv.x = f2bf(v0); lv.x = f2bf(v0 - bf2f(hv.x));
        hv.y = f2bf(v1); lv.y = f2bf(v1 - bf2f(hv.y));
        hv.z = f2bf(v2); lv.z = f2bf(v2 - bf2f(hv.z));
        hv.w = f2bf(v3); lv.w = f2bf(v3 - bf2f(hv.w));
        *(ushort4*)&sh[(size_t)d * ldo + q4] = hv;
        *(ushort4*)&sl[(size_t)d * ldo + q4] = lv;
    }
}

// ---------------------------------------------------------------------------
extern "C" void kernel_launch(void* const* d_in, const int* in_sizes, int n_in,
                              void* d_out, int out_size, void* d_ws, size_t ws_size,
                              hipStream_t stream) {
    const float* x      = (const float*)d_in[0];
    const int*   ei     = (const int*)d_in[1];
    const float* w1_l   = (const float*)d_in[2];
    const float* b1_l   = (const float*)d_in[3];
    const float* w1_r   = (const float*)d_in[4];
    const float* b1_r   = (const float*)d_in[5];
    const float* att1   = (const float*)d_in[6];
    const float* bias1  = (const float*)d_in[7];
    const float* w2_l   = (const float*)d_in[8];
    const float* b2_l   = (const float*)d_in[9];
    const float* w2_r   = (const float*)d_in[10];
    const float* b2_r   = (const float*)d_in[11];
    const float* att2   = (const float*)d_in[12];
    const float* bias2  = (const float*)d_in[13];
    const float* w_lin  = (const float*)d_in[14];
    const float* b_lin  = (const float*)d_in[15];
    float* out = (float*)d_out;

    // ---- workspace layout (~130 MB) ----
    float* h1   = (float*)d_ws;                        // [N][512]  61.44 MB
    float* bufA = h1 + (size_t)N_NODES * F1;           // [N][256]  30.72 MB
    float* bufB = bufA + (size_t)N_NODES * OUT_F;      // [N][256]  30.72 MB
    unsigned short* wt1h = (unsigned short*)(bufB + (size_t)N_NODES * OUT_F);
    unsigned short* wt1l = wt1h + 8 * 65536;
    unsigned short* wt2h = wt1l + 8 * 65536;
    unsigned short* wt2l = wt2h + 4 * 131072;
    unsigned short* wtLh = wt2l + 4 * 131072;
    unsigned short* wtLl = wtLh + 65536;
    int* count   = (int*)(wtLl + 65536);
    int* offsets = count + T_TYPES * N_NODES;
    int* bsum    = offsets + T_TYPES * (N_NODES + 1);
    int* csr     = bsum + T_TYPES * SCAN_NB;
    // h2 split overlays h1's storage (h1 fp32 is dead once conv2 GEMMs read it)
    unsigned short* h2s_hi = (unsigned short*)h1;
    unsigned short* h2s_lo = h2s_hi + (size_t)N_NODES * OUT_F;

    // --- prep (weights split + count zero) ---
    prep_kernel<<<(PREP_TOT + 255) / 256, 256, 0, stream>>>(
        w1_l, w1_r, w2_l, w2_r, w_lin, wt1h, wt1l, wt2h, wt2l, wtLh, wtLl, count);

    // --- build CSR (by dst), shared by both convs ---
    int eblocks = (T_TYPES * EP + 255) / 256;
    hist_kernel<<<eblocks, 256, 0, stream>>>(ei, count);
    dim3 sgrid(SCAN_NB, T_TYPES);
    scan_bsum_kernel<<<sgrid, 256, 0, stream>>>(count, bsum);
    scan_base_kernel<<<1, 64, 0, stream>>>(bsum);
    scan_write_kernel<<<sgrid, 256, 0, stream>>>(count, bsum, offsets);
    scatter_kernel<<<eblocks, 256, 0, stream>>>(ei, offsets, count, csr);

    int gat_blocks = N_NODES / 4;
    dim3 ggrid((N_NODES + 63) / 64, 2);   // dual-output GEMM
    dim3 ggrid1((N_NODES + 63) / 64, 1);  // single-output GEMM

    // --- conv1: per (t, head-half): l+r GEMMs in one launch, then edge kernel ---
    for (int t = 0; t < T_TYPES; ++t) {
        for (int hh = 0; hh < 2; ++hh) {
            int co = hh * 256;
            int ml = (t * 2 + 0) * 2 + hh, mr = (t * 2 + 1) * 2 + hh;
            gemm_mfma_kernel<0><<<ggrid, 256, 0, stream>>>(
                x, nullptr, D_IN,
                wt1h + (size_t)ml * 65536, wt1l + (size_t)ml * 65536, b1_l + t * F1 + co, bufA,
                wt1h + (size_t)mr * 65536, wt1l + (size_t)mr * 65536, b1_r + t * F1 + co, bufB,
                N_NODES, D_IN);
            if (t == 0)
                gat_edge_kernel<16, 0><<<gat_blocks, 256, 0, stream>>>(
                    bufA, bufB, att1 + t * F1 + co, offsets + t * (N_NODES + 1),
                    csr + (size_t)t * EP, h1 + co, F1, nullptr, nullptr, nullptr, nullptr);
            else
                gat_edge_kernel<16, 2><<<gat_blocks, 256, 0, stream>>>(
                    bufA, bufB, att1 + t * F1 + co, offsets + t * (N_NODES + 1),
                    csr + (size_t)t * EP, h1 + co, F1, bias1 + co, bias1 + F1 + co,
                    nullptr, nullptr);
        }
    }

    // --- conv2 (1 head, 256 cols); t1 edge writes pre-split h2 ---
    for (int t = 0; t < T_TYPES; ++t) {
        int ml = t * 2 + 0, mr = t * 2 + 1;
        gemm_mfma_kernel<0><<<ggrid, 256, 0, stream>>>(
            h1, nullptr, F1,
            wt2h + (size_t)ml * 131072, wt2l + (size_t)ml * 131072, b2_l + t * OUT_F, bufA,
            wt2h + (size_t)mr * 131072, wt2l + (size_t)mr * 131072, b2_r + t * OUT_F, bufB,
            N_NODES, F1);
        if (t == 0)
            gat_edge_kernel<64, 0><<<gat_blocks, 256, 0, stream>>>(
                bufA, bufB, att2 + t * OUT_F, offsets + t * (N_NODES + 1),
                csr + (size_t)t * EP, out, OUT_F, nullptr, nullptr, nullptr, nullptr);
        else
            gat_edge_kernel<64, 3><<<gat_blocks, 256, 0, stream>>>(
                bufA, bufB, att2 + t * OUT_F, offsets + t * (N_NODES + 1),
                csr + (size_t)t * EP, out, OUT_F, bias2, bias2 + OUT_F,
                h2s_hi, h2s_lo);
    }

    // --- final linear: reads pre-split h2 via DMA path, writes d_out ---
    gemm_mfma_kernel<1><<<ggrid1, 256, 0, stream>>>(
        h2s_hi, h2s_lo, OUT_F,
        wtLh, wtLl, b_lin, out,
        wtLh, wtLl, b_lin, out,
        N_NODES, OUT_F);
}